// Round 4
// baseline (395.229 us; speedup 1.0000x reference)
//
#include <hip/hip_runtime.h>
#include <hip/hip_bf16.h>

typedef __attribute__((ext_vector_type(8)))  short bf16x8;
typedef __attribute__((ext_vector_type(16))) float f32x16;
typedef __attribute__((ext_vector_type(4)))  float f32x4;
typedef __attribute__((ext_vector_type(2)))  __fp16 fp16x2;

#define NN 50000
#define EE 800000
#define HH 128
#define KK 320   /* 2H + B */
#define NEG 0.01f
#define NTILES (EE / 64)
#define NBLK 1024   /* 256 CU x 4 resident blocks */
#define ACC_BYTES ((size_t)NN * HH * 2)   /* f16 accumulator ws region */

__device__ __forceinline__ unsigned pack2(float a, float b) {
    unsigned short lo = __builtin_bit_cast(unsigned short, __float2bfloat16(a));
    unsigned short hi = __builtin_bit_cast(unsigned short, __float2bfloat16(b));
    return (unsigned)lo | ((unsigned)hi << 16);
}

// feat f32 [NN,128] -> bf16 bits [NN,128]; 800000 threads x 8 elems
__global__ __launch_bounds__(256) void featcvt_kernel(const float* __restrict__ feat,
                                                      ushort* __restrict__ featb)
{
    const int t = blockIdx.x * 256 + threadIdx.x;
    const float* p = feat + (long long)t * 8;
    f32x4 v0 = *(const f32x4*)p;
    f32x4 v1 = *(const f32x4*)(p + 4);
    int4 h;
    h.x = (int)pack2(v0[0], v0[1]); h.y = (int)pack2(v0[2], v0[3]);
    h.z = (int)pack2(v1[0], v1[1]); h.w = (int)pack2(v1[2], v1[3]);
    *(int4*)(featb + (long long)t * 8) = h;
}

template<int USE_F16, int FEATB>
__global__ __launch_bounds__(256, 4) void fused_edge_kernel(
    const float*  __restrict__ feat, const ushort* __restrict__ featb,
    const float*  __restrict__ gdf,
    const float*  __restrict__ W,    const float* __restrict__ bias,
    const int*    __restrict__ src,  const int*   __restrict__ dst,
    float* __restrict__ out, __fp16* __restrict__ acc16)
{
    __shared__ int4 lds4[64 * 40];   // 64 rows x 640B (320 bf16) = 40960B exactly
    char* lds = (char*)lds4;

    const int tid  = threadIdx.x;
    const int lane = tid & 63;
    const int wid  = tid >> 6;               // wave owns cols [wid*32, wid*32+32)
    const int col  = wid * 32 + (lane & 31);
    const int khalf = lane >> 5;             // which 8-wide k-half of each k16 step
    const int r = tid >> 2, q = tid & 3;     // 4 threads per edge row (staging)

    // ---- W fragments for this wave's 32 columns (f32 -> bf16, in VGPRs, once) ----
    bf16x8 Wb[20];
    {
        const float* wrow = W + col * KK + khalf * 8;
        #pragma unroll
        for (int k = 0; k < 20; k++) {
            f32x4 x0 = *(const f32x4*)(wrow + k * 16);
            f32x4 x1 = *(const f32x4*)(wrow + k * 16 + 4);
            union { bf16x8 v; unsigned u[4]; } t;
            t.u[0] = pack2(x0[0], x0[1]); t.u[1] = pack2(x0[2], x0[3]);
            t.u[2] = pack2(x1[0], x1[1]); t.u[3] = pack2(x1[2], x1[3]);
            Wb[k] = t.v;
        }
    }
    const float bv = bias[col];

    int tile = blockIdx.x;
    int sCur = src[(long long)tile * 64 + r];
    int dCur = dst[(long long)tile * 64 + r];

    while (tile < NTILES) {
        const long long ebase = (long long)tile * 64;

        // ---- stage A tile: [feat[src](128) | feat[dst](128) | gdf(64)] as bf16 ----
        {
            const float* ge = gdf + (ebase + r) * 64;
            if (FEATB) {
                const ushort* fs = featb + (long long)sCur * HH;
                const ushort* fd = featb + (long long)dCur * HH;
                #pragma unroll
                for (int i = 0; i < 8; i++) {        // c = q+i*4 in 0..31: bf16 direct
                    const int c = q + i * 4;
                    const ushort* p = (c < 16) ? (fs + c * 8) : (fd + (c - 16) * 8);
                    int4 h = *(const int4*)p;
                    *(int4*)(lds + r * 640 + ((c * 16) ^ ((r & 7) << 4))) = h;
                }
                #pragma unroll
                for (int i = 8; i < 10; i++) {       // c in 32..39: gdf f32 -> bf16
                    const int c = q + i * 4;
                    const float* p = ge + (c - 32) * 8;
                    f32x4 v0 = *(const f32x4*)p;
                    f32x4 v1 = *(const f32x4*)(p + 4);
                    int4 h;
                    h.x = (int)pack2(v0[0], v0[1]); h.y = (int)pack2(v0[2], v0[3]);
                    h.z = (int)pack2(v1[0], v1[1]); h.w = (int)pack2(v1[2], v1[3]);
                    *(int4*)(lds + r * 640 + ((c * 16) ^ ((r & 7) << 4))) = h;
                }
            } else {
                const float* fs = feat + (long long)sCur * HH;
                const float* fd = feat + (long long)dCur * HH;
                #pragma unroll
                for (int i = 0; i < 10; i++) {
                    const int c = q + i * 4;
                    const float* p = (c < 16) ? (fs + c * 8)
                                   : (c < 32) ? (fd + (c - 16) * 8)
                                              : (ge + (c - 32) * 8);
                    f32x4 v0 = *(const f32x4*)p;
                    f32x4 v1 = *(const f32x4*)(p + 4);
                    int4 h;
                    h.x = (int)pack2(v0[0], v0[1]); h.y = (int)pack2(v0[2], v0[3]);
                    h.z = (int)pack2(v1[0], v1[1]); h.w = (int)pack2(v1[2], v1[3]);
                    *(int4*)(lds + r * 640 + ((c * 16) ^ ((r & 7) << 4))) = h;
                }
            }
        }
        __syncthreads();

        // ---- prefetch next tile's indices (breaks idx->gather dep chain) ----
        const int nt = tile + NBLK;
        if (nt < NTILES) {
            sCur = src[(long long)nt * 64 + r];
            dCur = dst[(long long)nt * 64 + r];
        }

        // ---- MFMA: D[64 x 32cols] += A[64 x 320] * W^T slice ----
        f32x16 acc0 = {}; f32x16 acc1 = {};
        const int arow = lane & 31;
        const int xr   = (arow & 7) << 4;
        #pragma unroll
        for (int k = 0; k < 20; k++) {
            const int kb = k * 32 + khalf * 16;
            bf16x8 a0 = *(const bf16x8*)(lds + arow * 640 + (kb ^ xr));
            bf16x8 a1 = *(const bf16x8*)(lds + (arow + 32) * 640 + (kb ^ xr));
            acc0 = __builtin_amdgcn_mfma_f32_32x32x16_bf16(a0, Wb[k], acc0, 0, 0, 0);
            acc1 = __builtin_amdgcn_mfma_f32_32x32x16_bf16(a1, Wb[k], acc1, 0, 0, 0);
        }

        // ---- epilogue: bias + sigmoid*leakyrelu, scatter-add ----
        const int* dtile = dst + ebase;   // 64 ints, L1-hot (read last iter's prefetch)
        #pragma unroll
        for (int rt = 0; rt < 2; rt++) {
            const f32x16 A = rt ? acc1 : acc0;
            #pragma unroll
            for (int g = 0; g < 4; g++) {
                #pragma unroll
                for (int j = 0; j < 4; j++) {
                    const int reg = g * 4 + j;
                    const int row = j + g * 8 + khalf * 4;   // C/D row mapping
                    const float z  = A[reg] + bv;
                    const float lr = z > 0.f ? z : NEG * z;
                    const float sg = 1.f / (1.f + __expf(-z));
                    const float m  = lr * sg;
                    const int dn = dtile[rt * 32 + row];
                    if (USE_F16) {
                        const float o = __shfl_xor(m, 1);   // neighbor col's value
                        if (!(lane & 1)) {                  // even lane: cols (col, col+1)
                            fp16x2 hv = __builtin_amdgcn_cvt_pkrtz(m, o);
                            __fp16* p = acc16 + (long long)dn * HH + col;
                            asm volatile("global_atomic_pk_add_f16 %0, %1, off"
                                         :: "v"(p), "v"(hv) : "memory");
                        }
                    } else {
                        unsafeAtomicAdd(out + (long long)dn * HH + col, m);
                    }
                }
            }
        }
        __syncthreads();   // protect lds before next tile's staging
        tile = nt;
    }
}

__global__ __launch_bounds__(256) void conv_kernel(const int4* __restrict__ acc,
                                                   float4* __restrict__ out)
{
    const int i = blockIdx.x * 256 + threadIdx.x;   // 800000 threads x 8 halves
    union { int4 v; __fp16 h[8]; } u;
    u.v = acc[i];
    float4 a, b;
    a.x = (float)u.h[0]; a.y = (float)u.h[1]; a.z = (float)u.h[2]; a.w = (float)u.h[3];
    b.x = (float)u.h[4]; b.y = (float)u.h[5]; b.z = (float)u.h[6]; b.w = (float)u.h[7];
    out[2 * i]     = a;
    out[2 * i + 1] = b;
}

extern "C" void kernel_launch(void* const* d_in, const int* in_sizes, int n_in,
                              void* d_out, int out_size, void* d_ws, size_t ws_size,
                              hipStream_t stream) {
    const float* feat = (const float*)d_in[0];
    const float* gdf  = (const float*)d_in[1];
    const float* W    = (const float*)d_in[2];
    const float* bias = (const float*)d_in[3];
    const int*   src  = (const int*)d_in[4];
    const int*   dst  = (const int*)d_in[5];
    float* out = (float*)d_out;

    __fp16* acc16 = (__fp16*)d_ws;
    ushort* featb = (ushort*)((char*)d_ws + ACC_BYTES);

    if (ws_size >= 2 * ACC_BYTES) {
        // full path: bf16 feat + packed f16 atomics
        (void)hipMemsetAsync(d_ws, 0, ACC_BYTES, stream);
        featcvt_kernel<<<(NN * HH / 8) / 256 + 1, 256, 0, stream>>>(feat, featb);
        fused_edge_kernel<1, 1><<<NBLK, 256, 0, stream>>>(feat, featb, gdf, W, bias,
                                                          src, dst, out, acc16);
        conv_kernel<<<(NN * HH / 8) / 256, 256, 0, stream>>>((const int4*)d_ws,
                                                             (float4*)out);
    } else if (ws_size >= ACC_BYTES) {
        (void)hipMemsetAsync(d_ws, 0, ACC_BYTES, stream);
        fused_edge_kernel<1, 0><<<NBLK, 256, 0, stream>>>(feat, featb, gdf, W, bias,
                                                          src, dst, out, acc16);
        conv_kernel<<<(NN * HH / 8) / 256, 256, 0, stream>>>((const int4*)d_ws,
                                                             (float4*)out);
    } else {
        (void)hipMemsetAsync(out, 0, (size_t)out_size * sizeof(float), stream);
        fused_edge_kernel<0, 0><<<NBLK, 256, 0, stream>>>(feat, featb, gdf, W, bias,
                                                          src, dst, out, acc16);
    }
}

// Round 5
// 355.440 us; speedup vs baseline: 1.1119x; 1.1119x over previous
//
#include <hip/hip_runtime.h>
#include <hip/hip_bf16.h>

typedef __attribute__((ext_vector_type(8)))  short bf16x8;
typedef __attribute__((ext_vector_type(16))) float f32x16;
typedef __attribute__((ext_vector_type(4)))  float f32x4;
typedef __attribute__((ext_vector_type(2)))  __fp16 fp16x2;

#define NN 50000
#define EE 800000
#define HH 128
#define KK 320   /* 2H + B */
#define NEG 0.01f
#define NTILES (EE / 64)
#define NBLK 512            /* 256 CU x 2 resident blocks (80KB LDS each) */
#define ACC_BYTES ((size_t)NN * HH * 2)

__device__ __forceinline__ unsigned pack2(float a, float b) {
    unsigned short lo = __builtin_bit_cast(unsigned short, __float2bfloat16(a));
    unsigned short hi = __builtin_bit_cast(unsigned short, __float2bfloat16(b));
    return (unsigned)lo | ((unsigned)hi << 16);
}

// feat f32 [NN,128] -> bf16 bits; exactly 800000 threads x 8 elems = 3125 blocks
__global__ __launch_bounds__(256) void featcvt_kernel(const float* __restrict__ feat,
                                                      ushort* __restrict__ featb)
{
    const int t = blockIdx.x * 256 + threadIdx.x;
    const float* p = feat + (long long)t * 8;
    f32x4 v0 = *(const f32x4*)p;
    f32x4 v1 = *(const f32x4*)(p + 4);
    int4 h;
    h.x = (int)pack2(v0[0], v0[1]); h.y = (int)pack2(v0[2], v0[3]);
    h.z = (int)pack2(v1[0], v1[1]); h.w = (int)pack2(v1[2], v1[3]);
    *(int4*)(featb + (long long)t * 8) = h;
}

// Pipelined: reg-stage tile t+1 while computing tile t; double-buffered LDS,
// ONE barrier per tile. vmcnt wait for staged loads lands at the ds_write
// AFTER MFMA+epilogue -> gather latency hidden by ILP (T14).
__global__ __launch_bounds__(256, 2) void fused_pipe_kernel(
    const ushort* __restrict__ featb, const float* __restrict__ gdf,
    const float*  __restrict__ W,     const float* __restrict__ bias,
    const int*    __restrict__ src,   const int*   __restrict__ dst,
    __fp16* __restrict__ acc16)
{
    __shared__ int4 lds4[2][64 * 40];   // 2 x 40960B
    __shared__ int  dsts[2][64];

    const int tid  = threadIdx.x;
    const int lane = tid & 63;
    const int wid  = tid >> 6;
    const int col  = wid * 32 + (lane & 31);
    const int khalf = lane >> 5;
    const int r = tid >> 2, q = tid & 3;     // 4 threads per edge row

    // ---- W fragments (f32 -> bf16, VGPR/AGPR resident, loaded once) ----
    bf16x8 Wb[20];
    {
        const float* wrow = W + col * KK + khalf * 8;
        #pragma unroll
        for (int k = 0; k < 20; k++) {
            f32x4 x0 = *(const f32x4*)(wrow + k * 16);
            f32x4 x1 = *(const f32x4*)(wrow + k * 16 + 4);
            union { bf16x8 v; unsigned u[4]; } t;
            t.u[0] = pack2(x0[0], x0[1]); t.u[1] = pack2(x0[2], x0[3]);
            t.u[2] = pack2(x1[0], x1[1]); t.u[3] = pack2(x1[2], x1[3]);
            Wb[k] = t.v;
        }
    }
    const float bv = bias[col];

    int4  sf[8];   // staged feat chunks (bf16), c = q+4i in 0..31
    f32x4 sg[4];   // staged gdf (f32, packed at ds_write time)
    int   dStage;  // dst idx of the staged row

    auto issueLoads = [&](int t, int s_i, int d_i) {
        const ushort* fs = featb + (long long)s_i * HH;
        const ushort* fd = featb + (long long)d_i * HH;
        const float*  ge = gdf + ((long long)t * 64 + r) * 64;
        #pragma unroll
        for (int i = 0; i < 8; i++) {
            const int c = q + i * 4;
            sf[i] = *(const int4*)((c < 16) ? (fs + c * 8) : (fd + (c - 16) * 8));
        }
        #pragma unroll
        for (int i = 0; i < 2; i++) {
            const int cg = q + i * 4;                 // gdf chunk 0..7
            sg[2 * i]     = *(const f32x4*)(ge + cg * 8);
            sg[2 * i + 1] = *(const f32x4*)(ge + cg * 8 + 4);
        }
    };
    auto writeStage = [&](int buf) {
        char* base = (char*)lds4[buf];
        const int xr = (r & 7) << 4;
        #pragma unroll
        for (int i = 0; i < 8; i++) {
            const int c = q + i * 4;
            *(int4*)(base + r * 640 + ((c * 16) ^ xr)) = sf[i];
        }
        #pragma unroll
        for (int i = 0; i < 2; i++) {
            const int c = 32 + q + i * 4;
            int4 h;
            h.x = (int)pack2(sg[2*i][0], sg[2*i][1]);
            h.y = (int)pack2(sg[2*i][2], sg[2*i][3]);
            h.z = (int)pack2(sg[2*i+1][0], sg[2*i+1][1]);
            h.w = (int)pack2(sg[2*i+1][2], sg[2*i+1][3]);
            *(int4*)(base + r * 640 + ((c * 16) ^ xr)) = h;
        }
        if (q == 0) dsts[buf][r] = dStage;
    };

    // ---- prologue: stage tile0 into buf0; prefetch idx for tile0+NBLK ----
    int tile = blockIdx.x;
    int sN = src[(long long)tile * 64 + r];
    int dN = dst[(long long)tile * 64 + r];
    issueLoads(tile, sN, dN);
    dStage = dN;
    int nt = tile + NBLK;
    {
        const int tc = (nt < NTILES) ? nt : 0;
        sN = src[(long long)tc * 64 + r];
        dN = dst[(long long)tc * 64 + r];
    }
    writeStage(0);
    __syncthreads();

    int cur = 0;
    const int arow = lane & 31;
    const int xa   = (arow & 7) << 4;

    while (true) {
        const bool hasNext = (nt < NTILES);
        if (hasNext) {
            issueLoads(nt, sN, dN);          // VMEM issued; waited at writeStage
            dStage = dN;
            const int nnt = nt + NBLK;
            const int tc = (nnt < NTILES) ? nnt : 0;
            sN = src[(long long)tc * 64 + r];
            dN = dst[(long long)tc * 64 + r];
        }

        // ---- MFMA: D[64 x 32cols] += A[64 x 320] * W^T slice ----
        char* abase = (char*)lds4[cur];
        f32x16 acc0 = {}; f32x16 acc1 = {};
        #pragma unroll
        for (int k = 0; k < 20; k++) {
            const int kb = k * 32 + khalf * 16;
            bf16x8 a0 = *(const bf16x8*)(abase + arow * 640 + (kb ^ xa));
            bf16x8 a1 = *(const bf16x8*)(abase + (arow + 32) * 640 + (kb ^ xa));
            acc0 = __builtin_amdgcn_mfma_f32_32x32x16_bf16(a0, Wb[k], acc0, 0, 0, 0);
            acc1 = __builtin_amdgcn_mfma_f32_32x32x16_bf16(a1, Wb[k], acc1, 0, 0, 0);
        }

        // ---- epilogue: gate + packed f16 scatter-atomics ----
        #pragma unroll
        for (int rt = 0; rt < 2; rt++) {
            const f32x16 A = rt ? acc1 : acc0;
            #pragma unroll
            for (int g = 0; g < 4; g++) {
                #pragma unroll
                for (int j = 0; j < 4; j++) {
                    const int reg = g * 4 + j;
                    const int row = j + g * 8 + khalf * 4;
                    const float z  = A[reg] + bv;
                    const float lr = z > 0.f ? z : NEG * z;
                    const float sg2 = 1.f / (1.f + __expf(-z));
                    const float m  = lr * sg2;
                    const float o  = __shfl_xor(m, 1);
                    const int dn = dsts[cur][rt * 32 + row];
                    if (!(lane & 1)) {
                        fp16x2 hv = __builtin_amdgcn_cvt_pkrtz(m, o);
                        __fp16* p = acc16 + (long long)dn * HH + col;
                        asm volatile("global_atomic_pk_add_f16 %0, %1, off"
                                     :: "v"(p), "v"(hv) : "memory");
                    }
                }
            }
        }

        if (!hasNext) break;
        writeStage(cur ^ 1);      // vmcnt wait happens HERE (loads long in flight)
        tile = nt; nt += NBLK; cur ^= 1;
        __syncthreads();          // single barrier per tile
    }
}

// Fallback (small ws): non-pipelined, f32 atomics straight into out
__global__ __launch_bounds__(256) void fused_fallback_kernel(
    const float* __restrict__ feat, const float* __restrict__ gdf,
    const float* __restrict__ W,    const float* __restrict__ bias,
    const int*   __restrict__ src,  const int*   __restrict__ dst,
    float* __restrict__ out)
{
    __shared__ int4 lds4[64 * 40];
    __shared__ int  dsts[64];
    char* lds = (char*)lds4;
    const int tid = threadIdx.x, lane = tid & 63, wid = tid >> 6;
    const int col = wid * 32 + (lane & 31), khalf = lane >> 5;
    const int r = tid >> 2, q = tid & 3;
    const long long ebase = (long long)blockIdx.x * 64;

    bf16x8 Wb[20];
    {
        const float* wrow = W + col * KK + khalf * 8;
        #pragma unroll
        for (int k = 0; k < 20; k++) {
            f32x4 x0 = *(const f32x4*)(wrow + k * 16);
            f32x4 x1 = *(const f32x4*)(wrow + k * 16 + 4);
            union { bf16x8 v; unsigned u[4]; } t;
            t.u[0] = pack2(x0[0], x0[1]); t.u[1] = pack2(x0[2], x0[3]);
            t.u[2] = pack2(x1[0], x1[1]); t.u[3] = pack2(x1[2], x1[3]);
            Wb[k] = t.v;
        }
    }
    const int s = src[ebase + r], d = dst[ebase + r];
    if (q == 0) dsts[r] = d;
    {
        const float* fs = feat + (long long)s * HH;
        const float* fd = feat + (long long)d * HH;
        const float* ge = gdf + (ebase + r) * 64;
        #pragma unroll
        for (int i = 0; i < 10; i++) {
            const int c = q + i * 4;
            const float* p = (c < 16) ? (fs + c * 8)
                           : (c < 32) ? (fd + (c - 16) * 8)
                                      : (ge + (c - 32) * 8);
            f32x4 v0 = *(const f32x4*)p;
            f32x4 v1 = *(const f32x4*)(p + 4);
            int4 h;
            h.x = (int)pack2(v0[0], v0[1]); h.y = (int)pack2(v0[2], v0[3]);
            h.z = (int)pack2(v1[0], v1[1]); h.w = (int)pack2(v1[2], v1[3]);
            *(int4*)(lds + r * 640 + ((c * 16) ^ ((r & 7) << 4))) = h;
        }
    }
    __syncthreads();
    f32x16 acc0 = {}; f32x16 acc1 = {};
    const int arow = lane & 31, xa = (arow & 7) << 4;
    #pragma unroll
    for (int k = 0; k < 20; k++) {
        const int kb = k * 32 + khalf * 16;
        bf16x8 a0 = *(const bf16x8*)(lds + arow * 640 + (kb ^ xa));
        bf16x8 a1 = *(const bf16x8*)(lds + (arow + 32) * 640 + (kb ^ xa));
        acc0 = __builtin_amdgcn_mfma_f32_32x32x16_bf16(a0, Wb[k], acc0, 0, 0, 0);
        acc1 = __builtin_amdgcn_mfma_f32_32x32x16_bf16(a1, Wb[k], acc1, 0, 0, 0);
    }
    const float bv = bias[col];
    #pragma unroll
    for (int rt = 0; rt < 2; rt++) {
        const f32x16 A = rt ? acc1 : acc0;
        #pragma unroll
        for (int g = 0; g < 4; g++) {
            #pragma unroll
            for (int j = 0; j < 4; j++) {
                const int reg = g * 4 + j;
                const int row = j + g * 8 + khalf * 4;
                const float z  = A[reg] + bv;
                const float lr = z > 0.f ? z : NEG * z;
                const float sgm = 1.f / (1.f + __expf(-z));
                unsafeAtomicAdd(out + (long long)dsts[rt * 32 + row] * HH + col, lr * sgm);
            }
        }
    }
}

__global__ __launch_bounds__(256) void conv_kernel(const int4* __restrict__ acc,
                                                   float4* __restrict__ out)
{
    const int i = blockIdx.x * 256 + threadIdx.x;   // exactly 800000 threads
    union { int4 v; __fp16 h[8]; } u;
    u.v = acc[i];
    float4 a, b;
    a.x = (float)u.h[0]; a.y = (float)u.h[1]; a.z = (float)u.h[2]; a.w = (float)u.h[3];
    b.x = (float)u.h[4]; b.y = (float)u.h[5]; b.z = (float)u.h[6]; b.w = (float)u.h[7];
    out[2 * i]     = a;
    out[2 * i + 1] = b;
}

extern "C" void kernel_launch(void* const* d_in, const int* in_sizes, int n_in,
                              void* d_out, int out_size, void* d_ws, size_t ws_size,
                              hipStream_t stream) {
    const float* feat = (const float*)d_in[0];
    const float* gdf  = (const float*)d_in[1];
    const float* W    = (const float*)d_in[2];
    const float* bias = (const float*)d_in[3];
    const int*   src  = (const int*)d_in[4];
    const int*   dst  = (const int*)d_in[5];
    float* out = (float*)d_out;

    __fp16* acc16 = (__fp16*)d_ws;
    ushort* featb = (ushort*)((char*)d_ws + ACC_BYTES);

    if (ws_size >= 2 * ACC_BYTES) {
        (void)hipMemsetAsync(d_ws, 0, ACC_BYTES, stream);
        featcvt_kernel<<<NN * HH / 8 / 256, 256, 0, stream>>>(feat, featb);
        fused_pipe_kernel<<<NBLK, 256, 0, stream>>>(featb, gdf, W, bias,
                                                    src, dst, acc16);
        conv_kernel<<<NN * HH / 8 / 256, 256, 0, stream>>>((const int4*)d_ws,
                                                           (float4*)out);
    } else {
        (void)hipMemsetAsync(out, 0, (size_t)out_size * sizeof(float), stream);
        fused_fallback_kernel<<<EE / 64, 256, 0, stream>>>(feat, gdf, W, bias,
                                                           src, dst, out);
    }
}